// Round 5
// baseline (194.447 us; speedup 1.0000x reference)
//
#include <hip/hip_runtime.h>

// B=2, N=96, D=64, H=4, DK=16
#define ELEM_B 589824    // 9216*64 floats per batch per tensor
#define TENS   1179648   // 2*ELEM_B floats per projected tensor
#define T_ROWS 18432     // total rows

// ---------------------------------------------------------------------------
// 32-row x 64-col projection tile (proven R2 version): dst = src @ W^T + b.
// 256 threads: c = t&63, rg = t>>6 owns 8 rows. W staged pitch-68.
// ---------------------------------------------------------------------------
__device__ __forceinline__ void proj_tile(
    const float* __restrict__ src, const float* __restrict__ w,
    const float* __restrict__ bias, float* __restrict__ dst,
    int row0, int t, float* sw, float* srow, float* sb)
{
#pragma unroll
    for (int j = 0; j < 4; ++j) {           // 1024 float4 slots of W
        const int s = t + j * 256;
        const int c = s >> 4, k4 = s & 15;
        *(float4*)&sw[c * 68 + k4 * 4] = *(const float4*)(w + s * 4);
    }
#pragma unroll
    for (int j = 0; j < 2; ++j) {           // 512 float4 slots of src rows
        const int s = t + j * 256;
        *(float4*)&srow[s * 4] = *(const float4*)(src + row0 * 64 + s * 4);
    }
    if (t < 64) sb[t] = bias[t];
    __syncthreads();

    const int c = t & 63, rg = t >> 6;
    float acc[8];
#pragma unroll
    for (int r = 0; r < 8; ++r) acc[r] = sb[c];
#pragma unroll
    for (int k4 = 0; k4 < 16; ++k4) {
        const float4 w4 = *(const float4*)&sw[c * 68 + k4 * 4];
#pragma unroll
        for (int r = 0; r < 8; ++r) {
            const float4 s4 = *(const float4*)&srow[(rg * 8 + r) * 64 + k4 * 4];
            acc[r] = fmaf(s4.x, w4.x, acc[r]);
            acc[r] = fmaf(s4.y, w4.y, acc[r]);
            acc[r] = fmaf(s4.z, w4.z, acc[r]);
            acc[r] = fmaf(s4.w, w4.w, acc[r]);
        }
    }
#pragma unroll
    for (int r = 0; r < 8; ++r)
        dst[(row0 + rg * 8 + r) * 64 + c] = acc[r];
}

__global__ __launch_bounds__(256) void proj4_kernel(
    const float* __restrict__ state,
    const float* __restrict__ w0, const float* __restrict__ b0,
    const float* __restrict__ w1, const float* __restrict__ b1,
    const float* __restrict__ w2, const float* __restrict__ b2,
    const float* __restrict__ w3, const float* __restrict__ b3,
    float* __restrict__ o0, float* __restrict__ o1,
    float* __restrict__ o2, float* __restrict__ o3)
{
    __shared__ float sw[64 * 68];
    __shared__ float srow[32 * 64];
    __shared__ float sb[64];
    const int mat  = blockIdx.x & 3;
    const int row0 = (blockIdx.x >> 2) * 32;
    const float* w = (mat == 0) ? w0 : (mat == 1) ? w1 : (mat == 2) ? w2 : w3;
    const float* b = (mat == 0) ? b0 : (mat == 1) ? b1 : (mat == 2) ? b2 : b3;
    float* o       = (mat == 0) ? o0 : (mat == 1) ? o1 : (mat == 2) ? o2 : o3;
    proj_tile(state, w, b, o, row0, threadIdx.x, sw, srow, sb);
}

__global__ __launch_bounds__(256) void proj1_kernel(
    const float* __restrict__ src, const float* __restrict__ w,
    const float* __restrict__ b, float* __restrict__ dst)
{
    __shared__ float sw[64 * 68];
    __shared__ float srow[32 * 64];
    __shared__ float sb[64];
    proj_tile(src, w, b, dst, blockIdx.x * 32, threadIdx.x, sw, srow, sb);
}

// ---------------------------------------------------------------------------
// Fused single-pass edge attention v2 (no P, no LDS, no barriers).
// 288 blocks x 256 threads (4 independent waves). bh = bid&7 -> XCD-pinned:
// each XCD's lk/rk/lv/rv working set (2.36 MB) fits its 4 MB L2.
// Wave unit u = (bid>>3)*4 + wave covers (xt = u%24 -> 4 x's, yt = u/24 -> 16
// y's). Lane = (y 0..15, dq 0..3); quad-butterfly dot16 + quad-shared exp
// (verified in R4). Explicit prefetch of all 10 float4 loads for iteration
// a+1 before consuming iteration a -> loads overlap compute (ILP, not TLP).
// ---------------------------------------------------------------------------
__global__ __launch_bounds__(256) void fused_attn_kernel(
    const float* __restrict__ lk, const float* __restrict__ rk,
    const float* __restrict__ lv, const float* __restrict__ rv,
    float* __restrict__ xb)
{
    const int bid = blockIdx.x;
    const int bh  = bid & 7;             // XCD pin
    const int grp = bid >> 3;            // 0..35
    const int t = threadIdx.x;
    const int u = grp * 4 + (t >> 6);    // wave unit 0..143
    const int lane = t & 63;
    const int xt = u % 24, yt = u / 24;
    const int x0 = xt * 4, y0 = yt * 16;
    const int b = bh >> 2, h = bh & 3;
    const int base = b * ELEM_B + h * 16;
    const int y = lane >> 2, dq = lane & 3;

    const float* rkp = rk + base + (y0 + y) * 64 + dq * 4;   // + a*6144
    const float* rvp = rv + base + (y0 + y) * 64 + dq * 4;
    const float* lkp[4];
    const float* lvp[4];
#pragma unroll
    for (int xi = 0; xi < 4; ++xi)
        lkp[xi] = lk + base + (size_t)(x0 + xi) * 6144 + dq * 4;   // + a*64
#pragma unroll
    for (int j = 0; j < 4; ++j)
        lvp[j] = lv + base + (size_t)(x0 + (dq ^ j)) * 6144 + dq * 4;

    float4 acc[4];
    float den[4];
#pragma unroll
    for (int j = 0; j < 4; ++j) {
        acc[j] = make_float4(0.f, 0.f, 0.f, 0.f);
        den[j] = 0.f;
    }

    // prefetch iteration 0
    float4 rk_c = *(const float4*)rkp;
    float4 rv_c = *(const float4*)rvp;
    float4 lk_c[4], lv_c[4];
#pragma unroll
    for (int xi = 0; xi < 4; ++xi) lk_c[xi] = *(const float4*)lkp[xi];
#pragma unroll
    for (int j = 0; j < 4; ++j)   lv_c[j]  = *(const float4*)lvp[j];

#pragma unroll 4
    for (int a = 0; a < 96; ++a) {
        // issue next iteration's 10 loads first (clamped: a=95 re-reads 95)
        const int an = (a < 95) ? a + 1 : 95;
        float4 rk_n = *(const float4*)(rkp + (size_t)an * 6144);
        float4 rv_n = *(const float4*)(rvp + (size_t)an * 6144);
        float4 lk_n[4], lv_n[4];
#pragma unroll
        for (int xi = 0; xi < 4; ++xi) lk_n[xi] = *(const float4*)(lkp[xi] + an * 64);
#pragma unroll
        for (int j = 0; j < 4; ++j)   lv_n[j]  = *(const float4*)(lvp[j] + an * 64);

        // compute with current registers
        float s[4];
#pragma unroll
        for (int xi = 0; xi < 4; ++xi) {
            const float4 l4 = lk_c[xi];
            float par = l4.x * rk_c.x;
            par = fmaf(l4.y, rk_c.y, par);
            par = fmaf(l4.z, rk_c.z, par);
            par = fmaf(l4.w, rk_c.w, par);
            float v = par + __shfl_xor(par, 1);
            s[xi] = v + __shfl_xor(v, 2);
        }
        const float sown = (dq == 0) ? s[0] : (dq == 1) ? s[1] : (dq == 2) ? s[2] : s[3];
        const float pown = __expf(sown * 0.25f);       // 1/sqrt(16)
        const float p1 = __shfl_xor(pown, 1);
        const float p2 = __shfl_xor(pown, 2);
        const float p3 = __shfl_xor(p1, 2);
        const float pj[4] = {pown, p1, p2, p3};

#pragma unroll
        for (int j = 0; j < 4; ++j) {
            const float p = pj[j];
            const float4 l4 = lv_c[j];
            den[j] += p;
            acc[j].x = fmaf(p * l4.x, rv_c.x, acc[j].x);
            acc[j].y = fmaf(p * l4.y, rv_c.y, acc[j].y);
            acc[j].z = fmaf(p * l4.z, rv_c.z, acc[j].z);
            acc[j].w = fmaf(p * l4.w, rv_c.w, acc[j].w);
        }

        // rotate prefetch registers
        rk_c = rk_n; rv_c = rv_n;
#pragma unroll
        for (int xi = 0; xi < 4; ++xi) lk_c[xi] = lk_n[xi];
#pragma unroll
        for (int j = 0; j < 4; ++j)   lv_c[j]  = lv_n[j];
    }

#pragma unroll
    for (int j = 0; j < 4; ++j) {
        const int xi = dq ^ j;
        const float inv = 1.0f / den[j];
        float4 o;
        o.x = acc[j].x * inv; o.y = acc[j].y * inv;
        o.z = acc[j].z * inv; o.w = acc[j].w * inv;
        *(float4*)(xb + base + (size_t)((x0 + xi) * 96 + y0 + y) * 64 + dq * 4) = o;
    }
}

extern "C" void kernel_launch(void* const* d_in, const int* in_sizes, int n_in,
                              void* d_out, int out_size, void* d_ws, size_t ws_size,
                              hipStream_t stream)
{
    const float* state = (const float*)d_in[0];
    const float* w_lk  = (const float*)d_in[1];
    const float* b_lk  = (const float*)d_in[2];
    const float* w_rk  = (const float*)d_in[3];
    const float* b_rk  = (const float*)d_in[4];
    const float* w_lv  = (const float*)d_in[5];
    const float* b_lv  = (const float*)d_in[6];
    const float* w_rv  = (const float*)d_in[7];
    const float* b_rv  = (const float*)d_in[8];
    const float* w_out = (const float*)d_in[9];
    const float* b_out = (const float*)d_in[10];
    float* out = (float*)d_out;

    float* ws = (float*)d_ws;
    float* lk = ws;
    float* rk = ws + (size_t)TENS;
    float* lv = ws + (size_t)2 * TENS;
    float* rv = ws + (size_t)3 * TENS;
    float* xb = ws + (size_t)4 * TENS;

    proj4_kernel<<<4 * (T_ROWS / 32), 256, 0, stream>>>(
        state, w_lk, b_lk, w_rk, b_rk, w_lv, b_lv, w_rv, b_rv, lk, rk, lv, rv);
    fused_attn_kernel<<<288, 256, 0, stream>>>(lk, rk, lv, rv, xb);
    proj1_kernel<<<T_ROWS / 32, 256, 0, stream>>>(xb, w_out, b_out, out);
}

// Round 6
// 161.737 us; speedup vs baseline: 1.2022x; 1.2022x over previous
//
#include <hip/hip_runtime.h>

// B=2, N=96, D=64, H=4, DK=16
#define ELEM_B 589824    // 9216*64 floats per batch per tensor
#define TENS   1179648   // 2*ELEM_B floats per projected tensor
#define T_ROWS 18432     // total rows

// ---------------------------------------------------------------------------
// 32-row x 64-col projection tile (proven R2 version): dst = src @ W^T + b.
// ---------------------------------------------------------------------------
__device__ __forceinline__ void proj_tile(
    const float* __restrict__ src, const float* __restrict__ w,
    const float* __restrict__ bias, float* __restrict__ dst,
    int row0, int t, float* sw, float* srow, float* sb)
{
#pragma unroll
    for (int j = 0; j < 4; ++j) {           // 1024 float4 slots of W
        const int s = t + j * 256;
        const int c = s >> 4, k4 = s & 15;
        *(float4*)&sw[c * 68 + k4 * 4] = *(const float4*)(w + s * 4);
    }
#pragma unroll
    for (int j = 0; j < 2; ++j) {           // 512 float4 slots of src rows
        const int s = t + j * 256;
        *(float4*)&srow[s * 4] = *(const float4*)(src + row0 * 64 + s * 4);
    }
    if (t < 64) sb[t] = bias[t];
    __syncthreads();

    const int c = t & 63, rg = t >> 6;
    float acc[8];
#pragma unroll
    for (int r = 0; r < 8; ++r) acc[r] = sb[c];
#pragma unroll
    for (int k4 = 0; k4 < 16; ++k4) {
        const float4 w4 = *(const float4*)&sw[c * 68 + k4 * 4];
#pragma unroll
        for (int r = 0; r < 8; ++r) {
            const float4 s4 = *(const float4*)&srow[(rg * 8 + r) * 64 + k4 * 4];
            acc[r] = fmaf(s4.x, w4.x, acc[r]);
            acc[r] = fmaf(s4.y, w4.y, acc[r]);
            acc[r] = fmaf(s4.z, w4.z, acc[r]);
            acc[r] = fmaf(s4.w, w4.w, acc[r]);
        }
    }
#pragma unroll
    for (int r = 0; r < 8; ++r)
        dst[(row0 + rg * 8 + r) * 64 + c] = acc[r];
}

__global__ __launch_bounds__(256) void proj4_kernel(
    const float* __restrict__ state,
    const float* __restrict__ w0, const float* __restrict__ b0,
    const float* __restrict__ w1, const float* __restrict__ b1,
    const float* __restrict__ w2, const float* __restrict__ b2,
    const float* __restrict__ w3, const float* __restrict__ b3,
    float* __restrict__ o0, float* __restrict__ o1,
    float* __restrict__ o2, float* __restrict__ o3)
{
    __shared__ float sw[64 * 68];
    __shared__ float srow[32 * 64];
    __shared__ float sb[64];
    const int mat  = blockIdx.x & 3;
    const int row0 = (blockIdx.x >> 2) * 32;
    const float* w = (mat == 0) ? w0 : (mat == 1) ? w1 : (mat == 2) ? w2 : w3;
    const float* b = (mat == 0) ? b0 : (mat == 1) ? b1 : (mat == 2) ? b2 : b3;
    float* o       = (mat == 0) ? o0 : (mat == 1) ? o1 : (mat == 2) ? o2 : o3;
    proj_tile(state, w, b, o, row0, threadIdx.x, sw, srow, sb);
}

__global__ __launch_bounds__(256) void proj1_kernel(
    const float* __restrict__ src, const float* __restrict__ w,
    const float* __restrict__ b, float* __restrict__ dst)
{
    __shared__ float sw[64 * 68];
    __shared__ float srow[32 * 64];
    __shared__ float sb[64];
    proj_tile(src, w, b, dst, blockIdx.x * 32, threadIdx.x, sw, srow, sb);
}

// ---------------------------------------------------------------------------
// Scores (proven R2 kernel + XCD pin): block per (bh, a), bh = bid&7 so each
// bh's P slice stays in one XCD's L2. P layout: [bh][x][a][y].
// P[bh,x,a,y] = exp(S/4); no max-subtract (|S| << 1 by construction).
// ---------------------------------------------------------------------------
__global__ __launch_bounds__(384) void scores_kernel(
    const float* __restrict__ lk, const float* __restrict__ rk,
    float* __restrict__ P)
{
    __shared__ float lks[96][16];
    const int bid = blockIdx.x;
    const int bh = bid & 7;              // XCD pin
    const int a  = bid >> 3;             // 0..95
    const int b  = bh >> 2, h = bh & 3;
    const int t  = threadIdx.x;
    const int base = b * ELEM_B + h * 16;

    {   // stage lk[x=0..95][16]
        const int row = t >> 2, q = t & 3;
        *(float4*)&lks[row][q * 4] =
            *(const float4*)(lk + base + (row * 96 + a) * 64 + q * 4);
    }
    const int y = t % 96, xg = t / 96;
    const float4* rkp = (const float4*)(rk + base + (a * 96 + y) * 64);
    const float4 r0 = rkp[0], r1 = rkp[1], r2 = rkp[2], r3 = rkp[3];
    __syncthreads();

    float* Pout = P + (size_t)(bh * 96) * 9216 + a * 96 + y;
#pragma unroll 4
    for (int i = 0; i < 24; ++i) {
        const int x = xg * 24 + i;
        const float4* lp = (const float4*)lks[x];
        const float4 l0 = lp[0], l1 = lp[1], l2 = lp[2], l3 = lp[3];
        float s = l0.x * r0.x;
        s = fmaf(l0.y, r0.y, s); s = fmaf(l0.z, r0.z, s); s = fmaf(l0.w, r0.w, s);
        s = fmaf(l1.x, r1.x, s); s = fmaf(l1.y, r1.y, s); s = fmaf(l1.z, r1.z, s);
        s = fmaf(l1.w, r1.w, s); s = fmaf(l2.x, r2.x, s); s = fmaf(l2.y, r2.y, s);
        s = fmaf(l2.z, r2.z, s); s = fmaf(l2.w, r2.w, s); s = fmaf(l3.x, r3.x, s);
        s = fmaf(l3.y, r3.y, s); s = fmaf(l3.z, r3.z, s); s = fmaf(l3.w, r3.w, s);
        Pout[(size_t)x * 9216] = __expf(s * 0.25f);
    }
}

// ---------------------------------------------------------------------------
// Contraction v5: O[x,y,d] = (sum_a P*lv*rv) / (sum_a P).
// 1152 blocks x 256 threads = 4608 waves = 18 waves/CU. bh = bid&7 (XCD pin:
// reads P from the L2 that scores wrote it to). Thread = (dq = t&3,
// y = (t>>2)&15, xi = t>>6). lv staged once in LDS (24 KB, 1 barrier total).
// rv/P streamed from global through a fully-unrolled DEPTH-8 register ring
// (no barriers, no cross-lane ops) -> ~8 iterations of loads in flight.
// ---------------------------------------------------------------------------
__global__ __launch_bounds__(256) void contract_kernel(
    const float* __restrict__ lv, const float* __restrict__ rv,
    const float* __restrict__ P, float* __restrict__ xb)
{
    __shared__ float lvs[4][96][16];
    const int bid = blockIdx.x;
    const int bh = bid & 7;              // XCD pin
    const int r  = bid >> 3;             // 0..143
    const int xt = r % 24, yt = r / 24;  // yt 0..5
    const int b = bh >> 2, h = bh & 3;
    const int x0 = xt * 4, y0 = yt * 16;
    const int t = threadIdx.x;
    const int base = b * ELEM_B + h * 16;

    {   // stage lv[4][96][16]: 1536 float4 slots, 6 per thread
        const int aa = t >> 2, q = t & 3;         // aa 0..63, q 0..3
#pragma unroll
        for (int j = 0; j < 4; ++j)
            *(float4*)&lvs[j][aa][q * 4] =
                *(const float4*)(lv + base + ((x0 + j) * 96 + aa) * 64 + q * 4);
        const int aa2 = 64 + (t >> 3), q2 = (t >> 1) & 3, xj = t & 1;  // aa2 64..95
#pragma unroll
        for (int j = 0; j < 2; ++j)
            *(float4*)&lvs[xj * 2 + j][aa2][q2 * 4] =
                *(const float4*)(lv + base + ((x0 + xj * 2 + j) * 96 + aa2) * 64 + q2 * 4);
    }
    __syncthreads();

    const int dq = t & 3;
    const int y  = (t >> 2) & 15;
    const int xi = t >> 6;
    const int yy = y0 + y;

    const float* rvp = rv + base + yy * 64 + dq * 4;                          // += a*6144
    const float* Pp  = P + (size_t)(bh * 96 + x0 + xi) * 9216 + yy;           // += a*96

    float4 acc = make_float4(0.f, 0.f, 0.f, 0.f);
    float den = 0.f;

    // depth-8 register ring for rv (float4) and P (scalar)
    float4 rvb[8];
    float  pb[8];
#pragma unroll
    for (int i = 0; i < 8; ++i) {
        rvb[i] = *(const float4*)(rvp + (size_t)i * 6144);
        pb[i]  = Pp[(size_t)i * 96];
    }
#pragma unroll
    for (int o = 0; o < 12; ++o) {
#pragma unroll
        for (int i = 0; i < 8; ++i) {
            const int a = o * 8 + i;
            const float4 r4 = rvb[i];
            const float  p  = pb[i];
            const float4 l4 = *(const float4*)&lvs[xi][a][dq * 4];
            if (a + 8 < 96) {                     // refill slot for a+8
                rvb[i] = *(const float4*)(rvp + (size_t)(a + 8) * 6144);
                pb[i]  = Pp[(size_t)(a + 8) * 96];
            }
            den += p;
            acc.x = fmaf(p * l4.x, r4.x, acc.x);
            acc.y = fmaf(p * l4.y, r4.y, acc.y);
            acc.z = fmaf(p * l4.z, r4.z, acc.z);
            acc.w = fmaf(p * l4.w, r4.w, acc.w);
        }
    }

    const float inv = 1.0f / den;
    float4 o4;
    o4.x = acc.x * inv; o4.y = acc.y * inv;
    o4.z = acc.z * inv; o4.w = acc.w * inv;
    *(float4*)(xb + base + ((x0 + xi) * 96 + yy) * 64 + dq * 4) = o4;
}

extern "C" void kernel_launch(void* const* d_in, const int* in_sizes, int n_in,
                              void* d_out, int out_size, void* d_ws, size_t ws_size,
                              hipStream_t stream)
{
    const float* state = (const float*)d_in[0];
    const float* w_lk  = (const float*)d_in[1];
    const float* b_lk  = (const float*)d_in[2];
    const float* w_rk  = (const float*)d_in[3];
    const float* b_rk  = (const float*)d_in[4];
    const float* w_lv  = (const float*)d_in[5];
    const float* b_lv  = (const float*)d_in[6];
    const float* w_rv  = (const float*)d_in[7];
    const float* b_rv  = (const float*)d_in[8];
    const float* w_out = (const float*)d_in[9];
    const float* b_out = (const float*)d_in[10];
    float* out = (float*)d_out;

    float* ws = (float*)d_ws;
    float* lk = ws;
    float* rk = ws + (size_t)TENS;
    float* lv = ws + (size_t)2 * TENS;
    float* rv = ws + (size_t)3 * TENS;
    float* xb = ws + (size_t)4 * TENS;
    float* P  = ws + (size_t)5 * TENS;   // [bh][x][a][y] = 8*96*96*96 floats

    proj4_kernel<<<4 * (T_ROWS / 32), 256, 0, stream>>>(
        state, w_lk, b_lk, w_rk, b_rk, w_lv, b_lv, w_rv, b_rv, lk, rk, lv, rv);
    scores_kernel<<<768, 384, 0, stream>>>(lk, rk, P);
    contract_kernel<<<1152, 256, 0, stream>>>(lv, rv, P, xb);
    proj1_kernel<<<T_ROWS / 32, 256, 0, stream>>>(xb, w_out, b_out, out);
}

// Round 7
// 136.141 us; speedup vs baseline: 1.4283x; 1.1880x over previous
//
#include <hip/hip_runtime.h>

// B=2, N=96, D=64, H=4, DK=16
#define ELEM_B 589824    // 9216*64 floats per batch per tensor
#define TENS   1179648   // 2*ELEM_B floats per projected tensor
#define T_ROWS 18432     // total rows
#define HM     147456    // 9216*16 floats per (b,h) head-major plane

// ---------------------------------------------------------------------------
// proj4: state (row-major) -> lk/rk/lv/rv in HEAD-MAJOR layout [bh][row][16].
// Compute identical to proven R2 proj_tile; only the store is re-indexed.
// ---------------------------------------------------------------------------
__global__ __launch_bounds__(256) void proj4_kernel(
    const float* __restrict__ state,
    const float* __restrict__ w0, const float* __restrict__ b0,
    const float* __restrict__ w1, const float* __restrict__ b1,
    const float* __restrict__ w2, const float* __restrict__ b2,
    const float* __restrict__ w3, const float* __restrict__ b3,
    float* __restrict__ o0, float* __restrict__ o1,
    float* __restrict__ o2, float* __restrict__ o3)
{
    __shared__ float sw[64 * 68];
    __shared__ float srow[32 * 64];
    __shared__ float sb[64];
    const int t = threadIdx.x;
    const int mat  = blockIdx.x & 3;
    const int row0 = (blockIdx.x >> 2) * 32;
    const float* w = (mat == 0) ? w0 : (mat == 1) ? w1 : (mat == 2) ? w2 : w3;
    const float* bi = (mat == 0) ? b0 : (mat == 1) ? b1 : (mat == 2) ? b2 : b3;
    float* o       = (mat == 0) ? o0 : (mat == 1) ? o1 : (mat == 2) ? o2 : o3;

#pragma unroll
    for (int j = 0; j < 4; ++j) {           // 1024 float4 slots of W
        const int s = t + j * 256;
        const int c = s >> 4, k4 = s & 15;
        *(float4*)&sw[c * 68 + k4 * 4] = *(const float4*)(w + s * 4);
    }
#pragma unroll
    for (int j = 0; j < 2; ++j) {           // 512 float4 slots of src rows
        const int s = t + j * 256;
        *(float4*)&srow[s * 4] = *(const float4*)(state + row0 * 64 + s * 4);
    }
    if (t < 64) sb[t] = bi[t];
    __syncthreads();

    const int c = t & 63, rg = t >> 6;
    float acc[8];
#pragma unroll
    for (int r = 0; r < 8; ++r) acc[r] = sb[c];
#pragma unroll
    for (int k4 = 0; k4 < 16; ++k4) {
        const float4 w4 = *(const float4*)&sw[c * 68 + k4 * 4];
#pragma unroll
        for (int r = 0; r < 8; ++r) {
            const float4 s4 = *(const float4*)&srow[(rg * 8 + r) * 64 + k4 * 4];
            acc[r] = fmaf(s4.x, w4.x, acc[r]);
            acc[r] = fmaf(s4.y, w4.y, acc[r]);
            acc[r] = fmaf(s4.z, w4.z, acc[r]);
            acc[r] = fmaf(s4.w, w4.w, acc[r]);
        }
    }
    // head-major store: [b*4+h][rbat][dk]
    const int b = row0 / 9216;               // blocks never straddle batches
    const int rbat0 = row0 - b * 9216 + rg * 8;
    const int h = c >> 4, dk = c & 15;
    float* dp = o + (size_t)(b * 4 + h) * HM + (size_t)rbat0 * 16 + dk;
#pragma unroll
    for (int r = 0; r < 8; ++r)
        dp[r * 16] = acc[r];
}

// ---------------------------------------------------------------------------
// proj1: out = xb @ w_out^T + b_out. xb is HEAD-MAJOR; out is row-major.
// Staging gathers the 4 h-slices of each row back into [row][64] order.
// ---------------------------------------------------------------------------
__global__ __launch_bounds__(256) void proj1_kernel(
    const float* __restrict__ xb, const float* __restrict__ w,
    const float* __restrict__ bi, float* __restrict__ out)
{
    __shared__ float sw[64 * 68];
    __shared__ float srow[32 * 64];
    __shared__ float sb[64];
    const int t = threadIdx.x;
    const int row0 = blockIdx.x * 32;

#pragma unroll
    for (int j = 0; j < 4; ++j) {
        const int s = t + j * 256;
        const int c = s >> 4, k4 = s & 15;
        *(float4*)&sw[c * 68 + k4 * 4] = *(const float4*)(w + s * 4);
    }
#pragma unroll
    for (int j = 0; j < 2; ++j) {           // gather head-major src rows
        const int s = t + j * 256;          // float4 slot
        const int rl = s >> 4;              // local row 0..31
        const int hc = s & 15;              // h = hc>>2, c4 = hc&3
        const int grow = row0 + rl;
        const int bb = grow / 9216;
        const int rb = grow - bb * 9216;
        const float4 v = *(const float4*)(xb + (size_t)(bb * 4 + (hc >> 2)) * HM
                                             + (size_t)rb * 16 + (hc & 3) * 4);
        *(float4*)&srow[rl * 64 + hc * 4] = v;
    }
    if (t < 64) sb[t] = bi[t];
    __syncthreads();

    const int c = t & 63, rg = t >> 6;
    float acc[8];
#pragma unroll
    for (int r = 0; r < 8; ++r) acc[r] = sb[c];
#pragma unroll
    for (int k4 = 0; k4 < 16; ++k4) {
        const float4 w4 = *(const float4*)&sw[c * 68 + k4 * 4];
#pragma unroll
        for (int r = 0; r < 8; ++r) {
            const float4 s4 = *(const float4*)&srow[(rg * 8 + r) * 64 + k4 * 4];
            acc[r] = fmaf(s4.x, w4.x, acc[r]);
            acc[r] = fmaf(s4.y, w4.y, acc[r]);
            acc[r] = fmaf(s4.z, w4.z, acc[r]);
            acc[r] = fmaf(s4.w, w4.w, acc[r]);
        }
    }
#pragma unroll
    for (int r = 0; r < 8; ++r)
        out[(row0 + rg * 8 + r) * 64 + c] = acc[r];
}

// ---------------------------------------------------------------------------
// Fused edge attention: scores + single-pass softmax + contraction, no P
// tensor. Block = (bh, 16 x's, 16 y's), 256 threads; thread = (xi, y) owns
// all 16 d. Grid = 8*6*6 = 288. a-loop in tiles of 8, register-double-
// buffered LDS staging (all loads contiguous thanks to head-major layout).
// LDS padding: lk/lv xi-pitch 132 words, rk/rv y-pitch 20 words -> worst
// bank pattern 2-way (free). No cross-lane ops anywhere.
// ---------------------------------------------------------------------------
__global__ __launch_bounds__(256) void fused_attn_kernel(
    const float* __restrict__ lk, const float* __restrict__ rk,
    const float* __restrict__ lv, const float* __restrict__ rv,
    float* __restrict__ xb)
{
    __shared__ float lkt[16 * 132];
    __shared__ float lvt[16 * 132];
    __shared__ float rkt[8 * 320];
    __shared__ float rvt[8 * 320];

    const int bid = blockIdx.x;
    const int bh = bid & 7;
    const int rest = bid >> 3;
    const int xt = rest % 6, yt = rest / 6;
    const int x0 = xt * 16, y0 = yt * 16;
    const int t = threadIdx.x;
    const int y = t & 15, xi = t >> 4;
    const size_t base = (size_t)bh * HM;

    // staging slots: 2 float4 slots per tensor per thread (512 slots/tile)
    const int s1 = t + 256;
    // lk/lv decomposition: xs = s>>5, as = (s>>2)&7, c4 = s&3
    const int xs0 = t >> 5,  as0 = (t >> 2) & 7,  c40 = t & 3;
    const int xs1 = s1 >> 5, as1 = (s1 >> 2) & 7, c41 = s1 & 3;
    // rk/rv decomposition: ar = s>>6, yr = (s>>2)&15, c4 = s&3
    const int ar0 = t >> 6,  yr0 = (t >> 2) & 15;
    const int ar1 = s1 >> 6, yr1 = (s1 >> 2) & 15;

    const float* glk0 = lk + base + ((x0 + xs0) * 96 + as0) * 16 + c40 * 4;
    const float* glk1 = lk + base + ((x0 + xs1) * 96 + as1) * 16 + c41 * 4;
    const float* glv0 = lv + base + ((x0 + xs0) * 96 + as0) * 16 + c40 * 4;
    const float* glv1 = lv + base + ((x0 + xs1) * 96 + as1) * 16 + c41 * 4;
    const float* grk0 = rk + base + (ar0 * 96 + y0 + yr0) * 16 + c40 * 4;
    const float* grk1 = rk + base + (ar1 * 96 + y0 + yr1) * 16 + c41 * 4;
    const float* grv0 = rv + base + (ar0 * 96 + y0 + yr0) * 16 + c40 * 4;
    const float* grv1 = rv + base + (ar1 * 96 + y0 + yr1) * 16 + c41 * 4;

    const int wl0 = xs0 * 132 + as0 * 16 + c40 * 4;
    const int wl1 = xs1 * 132 + as1 * 16 + c41 * 4;
    const int wr0 = ar0 * 320 + yr0 * 20 + c40 * 4;
    const int wr1 = ar1 * 320 + yr1 * 20 + c41 * 4;

    // preload tile 0
    float4 p_lk0 = *(const float4*)glk0, p_lk1 = *(const float4*)glk1;
    float4 p_lv0 = *(const float4*)glv0, p_lv1 = *(const float4*)glv1;
    float4 p_rk0 = *(const float4*)grk0, p_rk1 = *(const float4*)grk1;
    float4 p_rv0 = *(const float4*)grv0, p_rv1 = *(const float4*)grv1;

    float4 acc0 = {0.f,0.f,0.f,0.f}, acc1 = acc0, acc2 = acc0, acc3 = acc0;
    float den = 0.f;

    const int rdl = xi * 132;   // + ai*16 + c*4
    const int rdr = y * 20;     // + ai*320 + c*4

    for (int tile = 0; tile < 12; ++tile) {
        __syncthreads();
        *(float4*)&lkt[wl0] = p_lk0; *(float4*)&lkt[wl1] = p_lk1;
        *(float4*)&lvt[wl0] = p_lv0; *(float4*)&lvt[wl1] = p_lv1;
        *(float4*)&rkt[wr0] = p_rk0; *(float4*)&rkt[wr1] = p_rk1;
        *(float4*)&rvt[wr0] = p_rv0; *(float4*)&rvt[wr1] = p_rv1;
        __syncthreads();
        if (tile < 11) {        // prefetch next tile (overlaps compute)
            glk0 += 128;  glk1 += 128;  glv0 += 128;  glv1 += 128;
            grk0 += 12288; grk1 += 12288; grv0 += 12288; grv1 += 12288;
            p_lk0 = *(const float4*)glk0; p_lk1 = *(const float4*)glk1;
            p_lv0 = *(const float4*)glv0; p_lv1 = *(const float4*)glv1;
            p_rk0 = *(const float4*)grk0; p_rk1 = *(const float4*)grk1;
            p_rv0 = *(const float4*)grv0; p_rv1 = *(const float4*)grv1;
        }
#pragma unroll
        for (int ai = 0; ai < 8; ++ai) {
            const int lo = rdl + ai * 16;
            const int ro = ai * 320 + rdr;
            const float4 k0 = *(const float4*)&lkt[lo];
            const float4 k1 = *(const float4*)&lkt[lo + 4];
            const float4 k2 = *(const float4*)&lkt[lo + 8];
            const float4 k3 = *(const float4*)&lkt[lo + 12];
            const float4 q0 = *(const float4*)&rkt[ro];
            const float4 q1 = *(const float4*)&rkt[ro + 4];
            const float4 q2 = *(const float4*)&rkt[ro + 8];
            const float4 q3 = *(const float4*)&rkt[ro + 12];
            float s = k0.x * q0.x;
            s = fmaf(k0.y, q0.y, s); s = fmaf(k0.z, q0.z, s); s = fmaf(k0.w, q0.w, s);
            s = fmaf(k1.x, q1.x, s); s = fmaf(k1.y, q1.y, s); s = fmaf(k1.z, q1.z, s);
            s = fmaf(k1.w, q1.w, s); s = fmaf(k2.x, q2.x, s); s = fmaf(k2.y, q2.y, s);
            s = fmaf(k2.z, q2.z, s); s = fmaf(k2.w, q2.w, s); s = fmaf(k3.x, q3.x, s);
            s = fmaf(k3.y, q3.y, s); s = fmaf(k3.z, q3.z, s); s = fmaf(k3.w, q3.w, s);
            const float p = __expf(s * 0.25f);      // 1/sqrt(16); |s| << 1
            den += p;
            const float4 l0 = *(const float4*)&lvt[lo];
            const float4 l1 = *(const float4*)&lvt[lo + 4];
            const float4 l2 = *(const float4*)&lvt[lo + 8];
            const float4 l3 = *(const float4*)&lvt[lo + 12];
            const float4 v0 = *(const float4*)&rvt[ro];
            const float4 v1 = *(const float4*)&rvt[ro + 4];
            const float4 v2 = *(const float4*)&rvt[ro + 8];
            const float4 v3 = *(const float4*)&rvt[ro + 12];
            acc0.x = fmaf(p * l0.x, v0.x, acc0.x);
            acc0.y = fmaf(p * l0.y, v0.y, acc0.y);
            acc0.z = fmaf(p * l0.z, v0.z, acc0.z);
            acc0.w = fmaf(p * l0.w, v0.w, acc0.w);
            acc1.x = fmaf(p * l1.x, v1.x, acc1.x);
            acc1.y = fmaf(p * l1.y, v1.y, acc1.y);
            acc1.z = fmaf(p * l1.z, v1.z, acc1.z);
            acc1.w = fmaf(p * l1.w, v1.w, acc1.w);
            acc2.x = fmaf(p * l2.x, v2.x, acc2.x);
            acc2.y = fmaf(p * l2.y, v2.y, acc2.y);
            acc2.z = fmaf(p * l2.z, v2.z, acc2.z);
            acc2.w = fmaf(p * l2.w, v2.w, acc2.w);
            acc3.x = fmaf(p * l3.x, v3.x, acc3.x);
            acc3.y = fmaf(p * l3.y, v3.y, acc3.y);
            acc3.z = fmaf(p * l3.z, v3.z, acc3.z);
            acc3.w = fmaf(p * l3.w, v3.w, acc3.w);
        }
    }

    const float inv = 1.0f / den;
    float* op = xb + base + (size_t)((x0 + xi) * 96 + y0 + y) * 16;
    float4 o0; o0.x = acc0.x*inv; o0.y = acc0.y*inv; o0.z = acc0.z*inv; o0.w = acc0.w*inv;
    float4 o1; o1.x = acc1.x*inv; o1.y = acc1.y*inv; o1.z = acc1.z*inv; o1.w = acc1.w*inv;
    float4 o2; o2.x = acc2.x*inv; o2.y = acc2.y*inv; o2.z = acc2.z*inv; o2.w = acc2.w*inv;
    float4 o3; o3.x = acc3.x*inv; o3.y = acc3.y*inv; o3.z = acc3.z*inv; o3.w = acc3.w*inv;
    ((float4*)op)[0] = o0;
    ((float4*)op)[1] = o1;
    ((float4*)op)[2] = o2;
    ((float4*)op)[3] = o3;
}

extern "C" void kernel_launch(void* const* d_in, const int* in_sizes, int n_in,
                              void* d_out, int out_size, void* d_ws, size_t ws_size,
                              hipStream_t stream)
{
    const float* state = (const float*)d_in[0];
    const float* w_lk  = (const float*)d_in[1];
    const float* b_lk  = (const float*)d_in[2];
    const float* w_rk  = (const float*)d_in[3];
    const float* b_rk  = (const float*)d_in[4];
    const float* w_lv  = (const float*)d_in[5];
    const float* b_lv  = (const float*)d_in[6];
    const float* w_rv  = (const float*)d_in[7];
    const float* b_rv  = (const float*)d_in[8];
    const float* w_out = (const float*)d_in[9];
    const float* b_out = (const float*)d_in[10];
    float* out = (float*)d_out;

    float* ws = (float*)d_ws;
    float* lk = ws;                          // head-major [bh][row][16]
    float* rk = ws + (size_t)TENS;
    float* lv = ws + (size_t)2 * TENS;
    float* rv = ws + (size_t)3 * TENS;
    float* xb = ws + (size_t)4 * TENS;       // head-major

    proj4_kernel<<<4 * (T_ROWS / 32), 256, 0, stream>>>(
        state, w_lk, b_lk, w_rk, b_rk, w_lv, b_lv, w_rv, b_rv, lk, rk, lv, rv);
    fused_attn_kernel<<<288, 256, 0, stream>>>(lk, rk, lv, rv, xb);
    proj1_kernel<<<T_ROWS / 32, 256, 0, stream>>>(xb, w_out, b_out, out);
}